// Round 7
// baseline (16465.424 us; speedup 1.0000x reference)
//
#include <hip/hip_runtime.h>
#include <hip/hip_bf16.h>
#include <hip/hip_fp16.h>

typedef _Float16 f16;
typedef __attribute__((ext_vector_type(4))) _Float16 f16x4;
typedef __attribute__((ext_vector_type(8))) _Float16 f16x8;
typedef __attribute__((ext_vector_type(4))) float f32x4;

#define T_ 512
#define B_ 128
#define I_ 256
#define H_ 512
#define G3_ 1536
#define KC2 832     // Wc2 cols: [0,512) W_hh | 512 b_hh | 0 | [544,800) W_ih | 800 b_ih | 0
#define XOFF 544
#define KA2 544     // Wat2 cols: [0,512) W_att | 512 b_att | 0
#define NKT 26      // 26 k-tiles of 32 cover all 832 Wc2 columns
#define NFRAG (NKT*3)
#define TP 20       // transpose-tile row pitch (elements)
#define HSTR 128    // h_buf row stride in ull units (512 f16 = 128 ull)  [r6 bug: was 64]

#define MFMA16(a,b,c) __builtin_amdgcn_mfma_f32_16x16x32_f16((a),(b),(c),0,0,0)

__device__ __forceinline__ float fast_exp(float x){
  return __builtin_amdgcn_exp2f(x * 1.4426950408889634f);
}
__device__ __forceinline__ float sigm(float x){
  return __builtin_amdgcn_rcpf(1.f + fast_exp(-x));
}
__device__ __forceinline__ float tanh_f(float x){
  return 1.f - 2.f * __builtin_amdgcn_rcpf(1.f + fast_exp(2.f * x));
}

// ---------------- prep: fp16 weights (biases folded as extra K-columns) + fp16 x ----------------
__global__ void k_prep(const float* __restrict__ x, const float* __restrict__ Wih,
                       const float* __restrict__ Whh,
                       const float* __restrict__ bih, const float* __restrict__ bhh,
                       const float* __restrict__ Watt, const float* __restrict__ batt,
                       f16* __restrict__ Wc2, f16* __restrict__ Wat2, f16* __restrict__ x16){
  const int n1 = G3_ * KC2;
  const int n2 = H_ * KA2;
  const int n3 = B_ * T_ * I_;
  const int tot = n1 + n2 + n3;
  for (int i = blockIdx.x * blockDim.x + threadIdx.x; i < tot; i += gridDim.x * blockDim.x){
    if (i < n1){
      int r = i / KC2, k = i % KC2;
      float v;
      if      (k <  H_)   v = Whh[r * H_ + k];
      else if (k == H_)   v = bhh[r];
      else if (k <  XOFF) v = 0.f;
      else if (k <  800)  v = Wih[r * I_ + (k - XOFF)];
      else if (k == 800)  v = bih[r];
      else                v = 0.f;
      Wc2[i] = (f16)v;
    } else if (i < n1 + n2){
      int j = i - n1; int r = j / KA2, k = j % KA2;
      float v = (k < H_) ? Watt[r * H_ + k] : (k == H_ ? batt[r] : 0.f);
      Wat2[j] = (f16)v;
    } else {
      int j = i - n1 - n2;
      x16[j] = (f16)x[j];
    }
  }
}

// ---------------- probe: (lane,reg)->(row,col) D mapping ----------------
__global__ void k_probe(int* __restrict__ rtab, int* __restrict__ ctab){
  __shared__ __align__(16) f16 A[16][32];
  __shared__ __align__(16) f16 BT[16][32];
  const int l = threadIdx.x, l16 = l & 15, lg = l >> 4;
  for (int i = l; i < 512; i += 64){ ((f16*)A)[i] = (f16)0.f; ((f16*)BT)[i] = (f16)0.f; }
  __syncthreads();
  if (l < 16){
    A[l][0]  = (f16)(float)(16 * l);
    A[l][1]  = (f16)1.f;
    BT[l][0] = (f16)1.f;
    BT[l][1] = (f16)(float)l;
  }
  __syncthreads();
  f16x8 a = *(const f16x8*)&A[l16][lg * 8];
  f16x8 b = *(const f16x8*)&BT[l16][lg * 8];
  f32x4 z; z[0]=0.f; z[1]=0.f; z[2]=0.f; z[3]=0.f;
  f32x4 d = MFMA16(a, b, z);
  #pragma unroll
  for (int q = 0; q < 4; ++q){
    int code = (int)(d[q] + 0.5f);
    rtab[l * 4 + q] = code >> 4;
    ctab[l * 4 + q] = code & 15;
  }
}

// ---------------- recurrence: 256 cooperative WGs, MALL-resident h exchange, flag barrier --------
// WG (g=bid&7, c=bid>>3): batch rows [16g,16g+16), h-cols [16c,16c+16).
// h_buf: [2][8][16][HSTR] ull (parity, group, row; HSTR=128 ull = 512 f16). All h_buf traffic =
// relaxed AGENT 8B atomics (sc1 -> MALL coherent). Barrier: per-WG epoch flag (16B apart),
// store t+1 after s_waitcnt vmcnt(0); poll all 32 flags + ballot.
__global__ __launch_bounds__(64, 1) void k_rec(const f16* __restrict__ x16,
    const f16* __restrict__ Wc2, const int* __restrict__ rtab, const int* __restrict__ ctab,
    unsigned long long* __restrict__ h_buf, unsigned int* __restrict__ flags,
    f16* __restrict__ hs){
  const int bid = blockIdx.x;
  const int g = bid & 7, c = bid >> 3;
  const int b0 = g * 16, j0 = c * 16;
  const int lane = threadIdx.x, l16 = lane & 15, lg = lane >> 4;

  __shared__ __align__(16) f16 Wlin[NFRAG * 64 * 8];   // fragment-linear: (frag*64+lane)*8
  __shared__ __align__(16) f16 ttile[16 * TP];

  // stage weight fragments once (78 frags x 64 lanes x 16B = 78 KB)
  for (int f = 0; f < NFRAG; ++f){
    int kt = f / 3, gi = f - kt * 3;
    const f16* src = Wc2 + (size_t)(gi * H_ + j0 + l16) * KC2 + kt * 32 + lg * 8;
    *(f16x8*)&Wlin[(f * 64 + lane) * 8] = *(const f16x8*)src;
  }

  int rt[4], ct[4];
  #pragma unroll
  for (int q = 0; q < 4; ++q){ rt[q] = rtab[lane*4+q]; ct[q] = ctab[lane*4+q]; }

  f16x8 ones;
  #pragma unroll
  for (int e = 0; e < 8; ++e) ones[e] = (f16)0.f;
  if (lg == 0) ones[0] = (f16)1.f;   // bias k-slot (first col of a k-tile)

  float hold[4];
  #pragma unroll
  for (int q = 0; q < 4; ++q) hold[q] = 0.f;

  unsigned int* fbase = flags + g * 128;        // 32 flags * 4-uint stride (16B)
  const f16* xb = x16 + (size_t)(b0 + l16) * T_ * I_ + lg * 8;

  // prefetch x(0)
  f16x8 xr[8];
  #pragma unroll
  for (int kx = 0; kx < 8; ++kx) xr[kx] = *(const f16x8*)(xb + kx * 32);

  for (int t = 0; t < T_; ++t){
    // ---- wait: all 32 sibling flags >= t (h(t-1) published at MALL) ----
    if (t > 0){
      const unsigned int* fp = fbase + (lane & 31) * 4;
      while (true){
        unsigned int v = __hip_atomic_load(fp, __ATOMIC_RELAXED, __HIP_MEMORY_SCOPE_AGENT);
        if (__ballot(v < (unsigned int)t) == 0ull) break;
        __builtin_amdgcn_s_sleep(1);
      }
      asm volatile("" ::: "memory");
    }

    // ---- load h(t-1): 32 independent 8B agent loads (overlapped) ----
    const unsigned long long* hr =
        h_buf + (((size_t)((t & 1) ^ 1) * 8 + g) * 16 + l16) * HSTR + lg * 2;
    union { unsigned long long u[2]; f16x8 v; } ha[16];
    #pragma unroll
    for (int kt = 0; kt < 16; ++kt){
      ha[kt].u[0] = __hip_atomic_load(hr + kt * 8,     __ATOMIC_RELAXED, __HIP_MEMORY_SCOPE_AGENT);
      ha[kt].u[1] = __hip_atomic_load(hr + kt * 8 + 1, __ATOMIC_RELAXED, __HIP_MEMORY_SCOPE_AGENT);
    }

    f32x4 aR, aZ, aNh, aNx;
    #pragma unroll
    for (int q = 0; q < 4; ++q){ aR[q]=0.f; aZ[q]=0.f; aNh[q]=0.f; aNx[q]=0.f; }

    // h-part: k-tiles 0..15
    #pragma unroll 4
    for (int kt = 0; kt < 16; ++kt){
      f16x8 w0 = *(const f16x8*)&Wlin[((kt*3+0)*64 + lane)*8];
      f16x8 w1 = *(const f16x8*)&Wlin[((kt*3+1)*64 + lane)*8];
      f16x8 w2 = *(const f16x8*)&Wlin[((kt*3+2)*64 + lane)*8];
      aR  = MFMA16(ha[kt].v, w0, aR);
      aZ  = MFMA16(ha[kt].v, w1, aZ);
      aNh = MFMA16(ha[kt].v, w2, aNh);
    }
    // h-bias tile (k-tile 16, col 512)
    {
      f16x8 w0 = *(const f16x8*)&Wlin[((16*3+0)*64 + lane)*8];
      f16x8 w1 = *(const f16x8*)&Wlin[((16*3+1)*64 + lane)*8];
      f16x8 w2 = *(const f16x8*)&Wlin[((16*3+2)*64 + lane)*8];
      aR  = MFMA16(ones, w0, aR);
      aZ  = MFMA16(ones, w1, aZ);
      aNh = MFMA16(ones, w2, aNh);
    }
    // x-part: k-tiles 17..24
    #pragma unroll 4
    for (int kx = 0; kx < 8; ++kx){
      int f = (17 + kx) * 3;
      f16x8 w0 = *(const f16x8*)&Wlin[((f+0)*64 + lane)*8];
      f16x8 w1 = *(const f16x8*)&Wlin[((f+1)*64 + lane)*8];
      f16x8 w2 = *(const f16x8*)&Wlin[((f+2)*64 + lane)*8];
      aR  = MFMA16(xr[kx], w0, aR);
      aZ  = MFMA16(xr[kx], w1, aZ);
      aNx = MFMA16(xr[kx], w2, aNx);
    }
    // x-bias tile (k-tile 25, col 800)
    {
      f16x8 w0 = *(const f16x8*)&Wlin[((25*3+0)*64 + lane)*8];
      f16x8 w1 = *(const f16x8*)&Wlin[((25*3+1)*64 + lane)*8];
      f16x8 w2 = *(const f16x8*)&Wlin[((25*3+2)*64 + lane)*8];
      aR  = MFMA16(ones, w0, aR);
      aZ  = MFMA16(ones, w1, aZ);
      aNx = MFMA16(ones, w2, aNx);
    }

    // ---- epilogue: gates -> h; transpose via LDS for coalesced publish ----
    #pragma unroll
    for (int q = 0; q < 4; ++q){
      float r  = sigm(aR[q]);
      float z  = sigm(aZ[q]);
      float nn = tanh_f(aNx[q] + r * aNh[q]);
      float h  = (1.f - z) * nn + z * hold[q];
      hold[q] = h;
      ttile[rt[q] * TP + ct[q]] = (f16)h;
    }
    asm volatile("s_waitcnt lgkmcnt(0)" ::: "memory");
    const int rr = lane >> 2, c4 = (lane & 3) * 4;
    f16x4 tv = *(const f16x4*)&ttile[rr * TP + c4];
    unsigned long long pk;
    __builtin_memcpy(&pk, &tv, 8);

    // hs: plain store (consumed after kernel end; end-of-dispatch flush covers it)
    *(unsigned long long*)(hs + ((size_t)t * B_ + b0 + rr) * H_ + j0 + c4) = pk;
    // h_buf: agent store -> MALL
    unsigned long long* hw =
        h_buf + (((size_t)(t & 1) * 8 + g) * 16 + rr) * HSTR + (unsigned)(j0 + c4) / 4;
    __hip_atomic_store(hw, pk, __ATOMIC_RELAXED, __HIP_MEMORY_SCOPE_AGENT);

    // ---- drain stores to coherence point, then publish epoch ----
    asm volatile("s_waitcnt vmcnt(0)" ::: "memory");
    if (lane == 0)
      __hip_atomic_store(fbase + c * 4, (unsigned int)(t + 1),
                         __ATOMIC_RELAXED, __HIP_MEMORY_SCOPE_AGENT);

    // ---- prefetch x(t+1) under the next poll ----
    if (t + 1 < T_){
      const f16* xrow = xb + (size_t)(t + 1) * I_;
      #pragma unroll
      for (int kx = 0; kx < 8; ++kx) xr[kx] = *(const f16x8*)(xrow + kx * 32);
    }
  }
}

// ---------------- fused attention: scores MFMA + e-transpose + vectorized weighted sum ----------
// 256 WGs: b = bid>>1, j-half = bid&1; wave wv owns 64 cols. No atomics; shfl reduction.
__global__ __launch_bounds__(256, 1) void k_att(const f16* __restrict__ hs,
    const f16* __restrict__ Wat2, const int* __restrict__ rtab, const int* __restrict__ ctab,
    float* __restrict__ out){
  const int b  = blockIdx.x >> 1;
  const int jh = blockIdx.x & 1;
  const int tid = threadIdx.x, wv = tid >> 6, lane = tid & 63, l16 = lane & 15, lg = lane >> 4;
  const int jb = jh * 256 + wv * 64;

  __shared__ __align__(16) float etile[4][16 * TP];

  int rt[4], ct[4];
  #pragma unroll
  for (int q = 0; q < 4; ++q){ rt[q] = rtab[lane*4+q]; ct[q] = ctab[lane*4+q]; }

  f16x8 ones;
  #pragma unroll
  for (int e = 0; e < 8; ++e) ones[e] = (f16)0.f;
  if (lg == 0) ones[0] = (f16)1.f;

  float num[4][4], den[4][4];
  #pragma unroll
  for (int nt = 0; nt < 4; ++nt)
    #pragma unroll
    for (int k = 0; k < 4; ++k){ num[nt][k] = 0.f; den[nt][k] = 0.f; }

  for (int tt = 0; tt < 32; ++tt){
    // A-fragments for this 16-row t-tile, hoisted across the 4 col-tiles
    f16x8 a[16];
    const f16* ar = hs + ((size_t)(tt*16 + l16) * B_ + b) * H_ + lg * 8;
    #pragma unroll
    for (int kt = 0; kt < 16; ++kt) a[kt] = *(const f16x8*)(ar + kt * 32);

    #pragma unroll
    for (int nt = 0; nt < 4; ++nt){
      f32x4 acc;
      #pragma unroll
      for (int q = 0; q < 4; ++q) acc[q] = 0.f;
      const f16* wr = Wat2 + (size_t)(jb + nt*16 + l16) * KA2 + lg * 8;
      #pragma unroll
      for (int kt = 0; kt < 16; ++kt){
        f16x8 bf = *(const f16x8*)(wr + kt * 32);
        acc = MFMA16(a[kt], bf, acc);
      }
      { f16x8 bf = *(const f16x8*)(wr + 512); acc = MFMA16(ones, bf, acc); }

      // e = exp(tanh(s)); transpose 16x16 e-tile so hv loads vectorize
      #pragma unroll
      for (int q = 0; q < 4; ++q)
        etile[wv][rt[q] * TP + ct[q]] = fast_exp(tanh_f(acc[q]));
      asm volatile("s_waitcnt lgkmcnt(0)" ::: "memory");
      f32x4 ev = *(const f32x4*)&etile[wv][(lane>>2) * TP + (lane & 3) * 4];
      const f16* hp = hs + ((size_t)(tt*16 + (lane>>2)) * B_ + b) * H_ + jb + nt*16 + (lane&3)*4;
      f16x4 hv = *(const f16x4*)hp;
      #pragma unroll
      for (int k = 0; k < 4; ++k){
        num[nt][k] = fmaf(ev[k], (float)hv[k], num[nt][k]);
        den[nt][k] += ev[k];
      }
    }
  }

  // reduce over the 16 lanes sharing (lane&3); lanes 0..3 write the 16 cols of each tile
  #pragma unroll
  for (int nt = 0; nt < 4; ++nt){
    #pragma unroll
    for (int k = 0; k < 4; ++k){
      float n = num[nt][k], d = den[nt][k];
      #pragma unroll
      for (int m = 4; m <= 32; m <<= 1){ n += __shfl_xor(n, m, 64); d += __shfl_xor(d, m, 64); }
      if (lane < 4) out[(size_t)b * H_ + jb + nt*16 + lane*4 + k] = n / d;
    }
  }
}

extern "C" void kernel_launch(void* const* d_in, const int* in_sizes, int n_in,
                              void* d_out, int out_size, void* d_ws, size_t ws_size,
                              hipStream_t stream){
  (void)in_sizes; (void)n_in; (void)out_size;
  const float* x    = (const float*)d_in[0];
  const float* Wih  = (const float*)d_in[1];
  const float* Whh  = (const float*)d_in[2];
  const float* bih  = (const float*)d_in[3];
  const float* bhh  = (const float*)d_in[4];
  const float* Watt = (const float*)d_in[5];
  const float* batt = (const float*)d_in[6];

  char* ws = (char*)d_ws;
  // layout (bytes):
  //   hs   : [T][B][H] f16          @ 0            (67,108,864)
  //   x16  : [B][T][I] f16          @ 67,108,864   (33,554,432)
  //   Wc2  : [1536][832] f16        @ 100,663,296  (2,555,904)
  //   Wat2 : [512][544] f16         @ 103,219,200  (557,056)
  //   rtab : int[256]               @ 103,776,256  (1,024)
  //   ctab : int[256]               @ 103,777,280  (1,024)
  //   h_buf: [2][8][16][128] ull    @ 103,778,304  (262,144)
  //   flags: uint[8][32] (16B ea)   @ 104,040,448  (4,096)
  const size_t OFF_HS  = 0ull;
  const size_t OFF_X16 = 67108864ull;
  const size_t OFF_WC2 = 100663296ull;
  const size_t OFF_WAT = 103219200ull;
  const size_t OFF_RT  = 103776256ull;
  const size_t OFF_CT  = 103777280ull;
  const size_t OFF_HB  = 103778304ull;
  const size_t OFF_FL  = 104040448ull;
  const size_t NEED    = 104044544ull;
  if (ws_size < NEED) return;

  f16* hs    = (f16*)(ws + OFF_HS);
  f16* x16   = (f16*)(ws + OFF_X16);
  f16* Wc2   = (f16*)(ws + OFF_WC2);
  f16* Wat2  = (f16*)(ws + OFF_WAT);
  int* rtab  = (int*)(ws + OFF_RT);
  int* ctab  = (int*)(ws + OFF_CT);
  unsigned long long* h_buf = (unsigned long long*)(ws + OFF_HB);
  unsigned int* flags = (unsigned int*)(ws + OFF_FL);

  // zero h(-1) state + epoch flags every launch (graph-replay deterministic)
  hipMemsetAsync(ws + OFF_HB, 0, 262144 + 4096, stream);

  k_prep <<<2048, 256, 0, stream>>>(x, Wih, Whh, bih, bhh, Watt, batt, Wc2, Wat2, x16);
  k_probe<<<1,    64,  0, stream>>>(rtab, ctab);

  {
    void* args[] = { (void*)&x16, (void*)&Wc2, (void*)&rtab, (void*)&ctab,
                     (void*)&h_buf, (void*)&flags, (void*)&hs };
    hipLaunchCooperativeKernel((const void*)k_rec, dim3(256), dim3(64), args, 0, stream);
  }

  k_att<<<256, 256, 0, stream>>>(hs, Wat2, rtab, ctab, (float*)d_out);
}